// Round 1
// baseline (383.480 us; speedup 1.0000x reference)
//
#include <hip/hip_runtime.h>

// Problem: B=8, C=512, H=W=64, NH=8, D=64, window 8x8 (Ws=64), N=4096.
// Pipeline: LN -> QKV proj (bf16 MFMA) -> RoPE -> windowed attention -> out proj + residual -> NCHW.
// Workspace need: ~99.2 MB. d_out (67MB) is reused as scratch for RoPE'd Q and K.

typedef unsigned short u16;
typedef __bf16 bf16x8 __attribute__((ext_vector_type(8)));
typedef float f32x4 __attribute__((ext_vector_type(4)));
typedef u16 u16x8 __attribute__((ext_vector_type(8)));

__device__ __forceinline__ u16 f2bf(float f) {
    __bf16 h = (__bf16)f;
    return __builtin_bit_cast(u16, h);
}
__device__ __forceinline__ float bf2f(u16 u) {
    return (float)__builtin_bit_cast(__bf16, u);
}
__device__ __forceinline__ f32x4 mfma16(bf16x8 a, bf16x8 b, f32x4 c) {
    return __builtin_amdgcn_mfma_f32_16x16x32_bf16(a, b, c, 0, 0, 0);
}

// ---------------------------------------------------------------------------
// Setup: bf16 weight copies, RoPE table (4096 x 64: [sin,cos] interleaved),
// relative-position bias expanded to (8, 64, 64).
// grid 4096 x 256 = 1048576 threads (== 4*512*512 weight elements)
// ---------------------------------------------------------------------------
__global__ __launch_bounds__(256) void setup_kernel(
    const float* __restrict__ Wq, const float* __restrict__ Wk,
    const float* __restrict__ Wv, const float* __restrict__ Wo,
    const float* __restrict__ btab,
    u16* __restrict__ wq, u16* __restrict__ wk,
    u16* __restrict__ wv, u16* __restrict__ wo,
    float* __restrict__ rope, float* __restrict__ biasf)
{
    int idx = blockIdx.x * 256 + threadIdx.x;
    {
        int w = idx >> 18, e = idx & 262143;
        const float* src = (w == 0) ? Wq : (w == 1) ? Wk : (w == 2) ? Wv : Wo;
        u16* dst = (w == 0) ? wq : (w == 1) ? wk : (w == 2) ? wv : wo;
        dst[e] = f2bf(src[e]);
    }
    if (idx < 131072) {  // rope: n = idx>>5, j = idx&31
        int n = idx >> 5, j = idx & 31;
        float inv = powf(10000.0f, -(float)j / 32.0f);
        float a = (float)n * inv;
        float s, c;
        sincosf(a, &s, &c);
        rope[n * 64 + 2 * j] = s;
        rope[n * 64 + 2 * j + 1] = c;
    }
    if (idx < 32768) {  // biasf[h][p][q]
        int q = idx & 63, pp = (idx >> 6) & 63, h = idx >> 12;
        int r1 = pp >> 3, c1 = pp & 7, r2 = q >> 3, c2 = q & 7;
        int ri = (r1 - r2 + 7) * 15 + (c1 - c2 + 7);
        biasf[idx] = btab[ri * 8 + h];
    }
}

// ---------------------------------------------------------------------------
// LayerNorm over C=512 with NCHW->(B,N,C) transpose, bf16 output.
// Block: 32 tokens. grid = B * 128 = 1024.
// ---------------------------------------------------------------------------
__global__ __launch_bounds__(256) void ln_kernel(
    const float* __restrict__ x, const float* __restrict__ g,
    const float* __restrict__ be, u16* __restrict__ out)
{
    __shared__ u16 sX[512 * 36];  // [c][token], stride 36 to spread banks
    __shared__ float sSum[256];
    __shared__ float sSq[256];
    __shared__ float sMu[32], sInv[32];

    const int tid = threadIdx.x;
    const int b = blockIdx.x >> 7, grp = blockIdx.x & 127;
    const int nbase = grp << 5;
    const int no = tid & 31, cg = tid >> 5;

    const float* xp = x + ((size_t)b << 21) + nbase + no;
    float sum = 0.f, sq = 0.f;
#pragma unroll 4
    for (int i = 0; i < 64; i++) {
        int c = (i << 3) + cg;
        float v = xp[(size_t)c << 12];
        sum += v;
        sq += v * v;
        sX[c * 36 + no] = f2bf(v);
    }
    sSum[tid] = sum;
    sSq[tid] = sq;
    __syncthreads();
    if (tid < 32) {
        float s = 0.f, q = 0.f;
#pragma unroll
        for (int k = 0; k < 8; k++) { s += sSum[k * 32 + tid]; q += sSq[k * 32 + tid]; }
        float mu = s * (1.f / 512.f);
        float var = q * (1.f / 512.f) - mu * mu;
        sMu[tid] = mu;
        sInv[tid] = rsqrtf(var + 1e-5f);
    }
    __syncthreads();

    const int t = tid & 31;
    const int chalf = (tid >> 5) << 3;  // 0..56 step 8
    float mu = sMu[t], inv = sInv[t];
    size_t orow = ((size_t)((b << 12) + nbase + t)) * 512;
#pragma unroll
    for (int it = 0; it < 8; it++) {
        int c0 = chalf + (it << 6);
        f32x4 g0 = *(const f32x4*)&g[c0];
        f32x4 g1 = *(const f32x4*)&g[c0 + 4];
        f32x4 e0 = *(const f32x4*)&be[c0];
        f32x4 e1 = *(const f32x4*)&be[c0 + 4];
        u16x8 o;
#pragma unroll
        for (int k = 0; k < 8; k++) {
            float v = bf2f(sX[(c0 + k) * 36 + t]);
            float gg = (k < 4) ? g0[k] : g1[k - 4];
            float bb = (k < 4) ? e0[k] : e1[k - 4];
            o[k] = f2bf((v - mu) * inv * gg + bb);
        }
        *(u16x8*)&out[orow + c0] = o;
    }
}

// ---------------------------------------------------------------------------
// GEMM: Out(M=32768, 512) = A(32768,512) @ W^T(512,512) + bias, bf16 in/out.
// 128x128 block tile, BK=32, 4 waves each 4x4 of 16x16x32 MFMA.
// Epilogue: LDS transpose (two 64-row halves) -> optional RoPE -> coalesced bf16 rows.
// grid (256, 4)
// ---------------------------------------------------------------------------
template <bool ROPE>
__global__ __launch_bounds__(256) void gemm_proj(
    const u16* __restrict__ A, const u16* __restrict__ Bw,
    const float* __restrict__ bias, const float* __restrict__ rope,
    u16* __restrict__ Out)
{
    __shared__ u16 sA[128 * 40];
    __shared__ u16 sB[128 * 40];
    __shared__ u16 sC[64 * 136];

    const int m0 = blockIdx.x * 128;
    const int n0 = blockIdx.y * 128;
    const int tid = threadIdx.x;
    const int lane = tid & 63, wave = tid >> 6;
    const int ln = lane & 15, lq = lane >> 4;
    const int wm = wave & 1, wn = wave >> 1;

    f32x4 acc[4][4] = {};

    for (int kt = 0; kt < 512; kt += 32) {
        __syncthreads();
#pragma unroll
        for (int ps = 0; ps < 2; ps++) {
            int idx = (ps << 8) + tid;
            int row = idx >> 2, seg = idx & 3;
            *(u16x8*)&sA[row * 40 + seg * 8] =
                *(const u16x8*)&A[(size_t)(m0 + row) * 512 + kt + seg * 8];
            *(u16x8*)&sB[row * 40 + seg * 8] =
                *(const u16x8*)&Bw[(size_t)(n0 + row) * 512 + kt + seg * 8];
        }
        __syncthreads();
        bf16x8 af[4], bfr[4];
#pragma unroll
        for (int i = 0; i < 4; i++)
            af[i] = *(const bf16x8*)&sA[(wm * 64 + i * 16 + ln) * 40 + lq * 8];
#pragma unroll
        for (int j = 0; j < 4; j++)
            bfr[j] = *(const bf16x8*)&sB[(wn * 64 + j * 16 + ln) * 40 + lq * 8];
#pragma unroll
        for (int i = 0; i < 4; i++)
#pragma unroll
            for (int j = 0; j < 4; j++)
                acc[i][j] = mfma16(af[i], bfr[j], acc[i][j]);
    }

    float bj[4];
#pragma unroll
    for (int j = 0; j < 4; j++) bj[j] = bias[n0 + wn * 64 + j * 16 + ln];

#pragma unroll
    for (int half = 0; half < 2; half++) {
        __syncthreads();
        if (wm == half) {
#pragma unroll
            for (int i = 0; i < 4; i++)
#pragma unroll
                for (int j = 0; j < 4; j++)
#pragma unroll
                    for (int r = 0; r < 4; r++)
                        sC[(i * 16 + lq * 4 + r) * 136 + wn * 64 + j * 16 + ln] =
                            f2bf(acc[i][j][r] + bj[j]);
        }
        __syncthreads();
#pragma unroll
        for (int it = 0; it < 4; it++) {
            int idx = it * 256 + tid;
            int row = idx >> 4;
            int cseg = (idx & 15) * 8;
            u16x8 v = *(const u16x8*)&sC[row * 136 + cseg];
            int t = m0 + half * 64 + row;
            float f[8];
#pragma unroll
            for (int k = 0; k < 8; k++) f[k] = bf2f(v[k]);
            if (ROPE) {
                int n = t & 4095;
                int d0 = cseg & 63;  // n0 is a multiple of 64
                const float* rp = &rope[n * 64 + d0];
                f32x4 r0 = *(const f32x4*)rp;        // sin0 cos0 sin1 cos1
                f32x4 r1 = *(const f32x4*)(rp + 4);  // sin2 cos2 sin3 cos3
#pragma unroll
                for (int p = 0; p < 4; p++) {
                    float sn = (p < 2) ? r0[2 * p] : r1[2 * (p - 2)];
                    float cs = (p < 2) ? r0[2 * p + 1] : r1[2 * (p - 2) + 1];
                    float x0 = f[2 * p], x1 = f[2 * p + 1];
                    f[2 * p] = x0 * cs - x1 * sn;
                    f[2 * p + 1] = x0 * sn + x1 * cs;
                }
            }
            u16x8 o;
#pragma unroll
            for (int k = 0; k < 8; k++) o[k] = f2bf(f[k]);
            *(u16x8*)&Out[(size_t)t * 512 + n0 + cseg] = o;
        }
    }
}

// ---------------------------------------------------------------------------
// Output projection GEMM + bias + residual(qn) + transpose to (B,C,N) f32.
// grid (256, 4)
// ---------------------------------------------------------------------------
__global__ __launch_bounds__(256) void gemm_out(
    const u16* __restrict__ A, const u16* __restrict__ Bw,
    const float* __restrict__ bias, const u16* __restrict__ qn,
    float* __restrict__ Out)
{
    __shared__ u16 sA[128 * 40];
    __shared__ u16 sB[128 * 40];

    const int m0 = blockIdx.x * 128;
    const int n0 = blockIdx.y * 128;
    const int tid = threadIdx.x;
    const int lane = tid & 63, wave = tid >> 6;
    const int ln = lane & 15, lq = lane >> 4;
    const int wm = wave & 1, wn = wave >> 1;

    f32x4 acc[4][4] = {};

    for (int kt = 0; kt < 512; kt += 32) {
        __syncthreads();
#pragma unroll
        for (int ps = 0; ps < 2; ps++) {
            int idx = (ps << 8) + tid;
            int row = idx >> 2, seg = idx & 3;
            *(u16x8*)&sA[row * 40 + seg * 8] =
                *(const u16x8*)&A[(size_t)(m0 + row) * 512 + kt + seg * 8];
            *(u16x8*)&sB[row * 40 + seg * 8] =
                *(const u16x8*)&Bw[(size_t)(n0 + row) * 512 + kt + seg * 8];
        }
        __syncthreads();
        bf16x8 af[4], bfr[4];
#pragma unroll
        for (int i = 0; i < 4; i++)
            af[i] = *(const bf16x8*)&sA[(wm * 64 + i * 16 + ln) * 40 + lq * 8];
#pragma unroll
        for (int j = 0; j < 4; j++)
            bfr[j] = *(const bf16x8*)&sB[(wn * 64 + j * 16 + ln) * 40 + lq * 8];
#pragma unroll
        for (int i = 0; i < 4; i++)
#pragma unroll
            for (int j = 0; j < 4; j++)
                acc[i][j] = mfma16(af[i], bfr[j], acc[i][j]);
    }

    int cj[4];
    float bj[4];
#pragma unroll
    for (int j = 0; j < 4; j++) {
        cj[j] = n0 + wn * 64 + j * 16 + ln;
        bj[j] = bias[cj[j]];
    }
#pragma unroll
    for (int i = 0; i < 4; i++) {
        int t0 = m0 + wm * 64 + i * 16 + lq * 4;
        int bb = t0 >> 12, nn = t0 & 4095;
#pragma unroll
        for (int j = 0; j < 4; j++) {
            f32x4 v;
#pragma unroll
            for (int r = 0; r < 4; r++)
                v[r] = acc[i][j][r] + bj[j] + bf2f(qn[(size_t)(t0 + r) * 512 + cj[j]]);
            *(f32x4*)&Out[((size_t)((bb << 9) + cj[j]) << 12) + nn] = v;
        }
    }
}

// ---------------------------------------------------------------------------
// Windowed attention: one block per (head, window). 4 waves; wave w owns
// query rows 16w..16w+15. QK^T and PV via 16x16x32 bf16 MFMA; P transits LDS.
// grid 4096 (h = bid&7, g = bid>>3)
// ---------------------------------------------------------------------------
__global__ __launch_bounds__(256) void attn_kernel(
    const u16* __restrict__ Q, const u16* __restrict__ K, const u16* __restrict__ V,
    const float* __restrict__ biasf, u16* __restrict__ Out)
{
    __shared__ u16 sQ[64 * 72];
    __shared__ u16 sK[64 * 72];
    __shared__ u16 sVT[64 * 72];  // transposed: [dim][token]
    __shared__ u16 sP[4][16 * 72];

    const int tid = threadIdx.x;
    const int h = blockIdx.x & 7;
    const int g = blockIdx.x >> 3;
    const int b = g >> 6, wi = g & 63;
    const int hn = wi >> 3, wn = wi & 7;
    const int nwbase = (b << 12) + (hn << 3) * 64 + (wn << 3);

    const int lane = tid & 63, wave = tid >> 6;
    const int ln = lane & 15, lq = lane >> 4;

    {  // stage Q, K, V^T
        int p = tid >> 2, seg = tid & 3;
        int t = nwbase + ((p >> 3) << 6) + (p & 7);
        size_t base = (size_t)t * 512 + h * 64 + seg * 16;
        u16x8 q0 = *(const u16x8*)&Q[base];
        u16x8 q1 = *(const u16x8*)&Q[base + 8];
        *(u16x8*)&sQ[p * 72 + seg * 16] = q0;
        *(u16x8*)&sQ[p * 72 + seg * 16 + 8] = q1;
        u16x8 k0 = *(const u16x8*)&K[base];
        u16x8 k1 = *(const u16x8*)&K[base + 8];
        *(u16x8*)&sK[p * 72 + seg * 16] = k0;
        *(u16x8*)&sK[p * 72 + seg * 16 + 8] = k1;
        u16x8 v0 = *(const u16x8*)&V[base];
        u16x8 v1 = *(const u16x8*)&V[base + 8];
#pragma unroll
        for (int k = 0; k < 8; k++) {
            sVT[(seg * 16 + k) * 72 + p] = v0[k];
            sVT[(seg * 16 + 8 + k) * 72 + p] = v1[k];
        }
    }
    __syncthreads();

    f32x4 s[4] = {};
#pragma unroll
    for (int ks = 0; ks < 2; ks++) {
        bf16x8 a = *(const bf16x8*)&sQ[(wave * 16 + ln) * 72 + ks * 32 + lq * 8];
#pragma unroll
        for (int j = 0; j < 4; j++) {
            bf16x8 bb = *(const bf16x8*)&sK[(j * 16 + ln) * 72 + ks * 32 + lq * 8];
            s[j] = mfma16(a, bb, s[j]);
        }
    }

    // scale + bias + row softmax (rows lq*4+r of this wave's 16-row strip)
    float sv[4][4];
#pragma unroll
    for (int r = 0; r < 4; r++) {
        const float* bp = &biasf[((h * 64 + wave * 16 + lq * 4 + r) << 6) + ln];
#pragma unroll
        for (int j = 0; j < 4; j++) sv[r][j] = s[j][r] * 0.125f + bp[j * 16];
    }
#pragma unroll
    for (int r = 0; r < 4; r++) {
        float m = fmaxf(fmaxf(sv[r][0], sv[r][1]), fmaxf(sv[r][2], sv[r][3]));
        m = fmaxf(m, __shfl_xor(m, 1));
        m = fmaxf(m, __shfl_xor(m, 2));
        m = fmaxf(m, __shfl_xor(m, 4));
        m = fmaxf(m, __shfl_xor(m, 8));
        float sum = 0.f;
#pragma unroll
        for (int j = 0; j < 4; j++) {
            sv[r][j] = __expf(sv[r][j] - m);
            sum += sv[r][j];
        }
        sum += __shfl_xor(sum, 1);
        sum += __shfl_xor(sum, 2);
        sum += __shfl_xor(sum, 4);
        sum += __shfl_xor(sum, 8);
        float rinv = 1.f / sum;
#pragma unroll
        for (int j = 0; j < 4; j++)
            sP[wave][(lq * 4 + r) * 72 + j * 16 + ln] = f2bf(sv[r][j] * rinv);
    }
    // wave-local LDS roundtrip: no __syncthreads needed (strip is private)

    f32x4 o[4] = {};
#pragma unroll
    for (int ks = 0; ks < 2; ks++) {
        bf16x8 a = *(const bf16x8*)&sP[wave][ln * 72 + ks * 32 + lq * 8];
#pragma unroll
        for (int jd = 0; jd < 4; jd++) {
            bf16x8 bb = *(const bf16x8*)&sVT[(jd * 16 + ln) * 72 + ks * 32 + lq * 8];
            o[jd] = mfma16(a, bb, o[jd]);
        }
    }

#pragma unroll
    for (int r = 0; r < 4; r++) {
        int p = wave * 16 + lq * 4 + r;
        int t = nwbase + ((p >> 3) << 6) + (p & 7);
        size_t base = (size_t)t * 512 + h * 64 + ln;
#pragma unroll
        for (int jd = 0; jd < 4; jd++) Out[base + jd * 16] = f2bf(o[jd][r]);
    }
}

// ---------------------------------------------------------------------------
extern "C" void kernel_launch(void* const* d_in, const int* in_sizes, int n_in,
                              void* d_out, int out_size, void* d_ws, size_t ws_size,
                              hipStream_t stream)
{
    const float* q    = (const float*)d_in[0];
    const float* kv   = (const float*)d_in[1];
    const float* g_q  = (const float*)d_in[2];
    const float* b_q  = (const float*)d_in[3];
    const float* g_kv = (const float*)d_in[4];
    const float* b_kv = (const float*)d_in[5];
    const float* Wq   = (const float*)d_in[6];
    const float* bq   = (const float*)d_in[7];
    const float* Wk   = (const float*)d_in[8];
    const float* bk   = (const float*)d_in[9];
    const float* Wv   = (const float*)d_in[10];
    const float* bv   = (const float*)d_in[11];
    const float* Wo   = (const float*)d_in[12];
    const float* bo   = (const float*)d_in[13];
    const float* btab = (const float*)d_in[14];

    char* ws = (char*)d_ws;
    u16* qn      = (u16*)(ws);                 // 33,554,432 B
    u16* kvn     = (u16*)(ws + 33554432);      // 33,554,432 B (reused as attn out)
    u16* Vv      = (u16*)(ws + 67108864);      // 33,554,432 B
    float* rope  = (float*)(ws + 100663296);   // 1,048,576 B
    float* biasf = (float*)(ws + 101711872);   // 131,072 B
    u16* wq      = (u16*)(ws + 101842944);     // 524,288 B
    u16* wk      = (u16*)(ws + 102367232);
    u16* wv      = (u16*)(ws + 102891520);
    u16* wo      = (u16*)(ws + 103415808);     // end: 103,940,096 B
    u16* aout    = kvn;                        // reuse after V-proj consumed kvn
    u16* Qr      = (u16*)d_out;                // d_out as scratch for Q (bf16)
    u16* Kr      = Qr + 16777216;              // and K; overwritten by gemm_out

    setup_kernel<<<4096, 256, 0, stream>>>(Wq, Wk, Wv, Wo, btab, wq, wk, wv, wo, rope, biasf);
    ln_kernel<<<1024, 256, 0, stream>>>(q, g_q, b_q, qn);
    ln_kernel<<<1024, 256, 0, stream>>>(kv, g_kv, b_kv, kvn);
    gemm_proj<true><<<dim3(256, 4), 256, 0, stream>>>(qn, wq, bq, rope, Qr);
    gemm_proj<true><<<dim3(256, 4), 256, 0, stream>>>(kvn, wk, bk, rope, Kr);
    gemm_proj<false><<<dim3(256, 4), 256, 0, stream>>>(kvn, wv, bv, rope, Vv);
    attn_kernel<<<4096, 256, 0, stream>>>(Qr, Kr, Vv, biasf, aout);
    gemm_out<<<dim3(256, 4), 256, 0, stream>>>(aout, wo, bo, qn, (float*)d_out);
}

// Round 2
// 365.602 us; speedup vs baseline: 1.0489x; 1.0489x over previous
//
#include <hip/hip_runtime.h>

// Problem: B=8, C=512, H=W=64, NH=8, D=64, window 8x8 (Ws=64), N=4096.
// LN -> QKV proj (bf16 MFMA, global_load_lds staging) -> RoPE -> windowed attn -> out proj + residual.
// Token dim is window-permuted (bit-swap n[8:6]<->n[5:3]) between projection and out-proj so the
// attention kernel sees fully contiguous 64-token windows. V is stored transposed (b,h,d,wpos).

typedef unsigned short u16;
typedef __bf16 bf16x8 __attribute__((ext_vector_type(8)));
typedef float f32x4 __attribute__((ext_vector_type(4)));
typedef u16 u16x8 __attribute__((ext_vector_type(8)));
typedef u16 u16x4 __attribute__((ext_vector_type(4)));

__device__ __forceinline__ u16 f2bf(float f) {
    __bf16 h = (__bf16)f;
    return __builtin_bit_cast(u16, h);
}
__device__ __forceinline__ float bf2f(u16 u) {
    return (float)__builtin_bit_cast(__bf16, u);
}
__device__ __forceinline__ f32x4 mfma16(bf16x8 a, bf16x8 b, f32x4 c) {
    return __builtin_amdgcn_mfma_f32_16x16x32_bf16(a, b, c, 0, 0, 0);
}
// async global->LDS, 16B per lane; LDS dest is wave-uniform base + lane*16.
__device__ __forceinline__ void gl_lds16(const u16* g, u16* l) {
    __builtin_amdgcn_global_load_lds((const __attribute__((address_space(1))) void*)g,
                                     (__attribute__((address_space(3))) void*)l, 16, 0, 0);
}
// window permutation: n = hn[11:9] r[8:6] wn[5:3] cc[2:0] -> hn wn r cc  (involution)
__device__ __forceinline__ int swapb(int n) {
    return (n & 0xE07) | ((n & 0x1C0) >> 3) | ((n & 0x038) << 3);
}

// ---------------------------------------------------------------------------
// Setup: bf16 weights, RoPE table (4096 x 64 [sin,cos] interleaved), bias (8,64,64).
// ---------------------------------------------------------------------------
__global__ __launch_bounds__(256) void setup_kernel(
    const float* __restrict__ Wq, const float* __restrict__ Wk,
    const float* __restrict__ Wv, const float* __restrict__ Wo,
    const float* __restrict__ btab,
    u16* __restrict__ wq, u16* __restrict__ wk,
    u16* __restrict__ wv, u16* __restrict__ wo,
    float* __restrict__ rope, float* __restrict__ biasf)
{
    int idx = blockIdx.x * 256 + threadIdx.x;
    {
        int w = idx >> 18, e = idx & 262143;
        const float* src = (w == 0) ? Wq : (w == 1) ? Wk : (w == 2) ? Wv : Wo;
        u16* dst = (w == 0) ? wq : (w == 1) ? wk : (w == 2) ? wv : wo;
        dst[e] = f2bf(src[e]);
    }
    if (idx < 131072) {
        int n = idx >> 5, j = idx & 31;
        float inv = powf(10000.0f, -(float)j / 32.0f);
        float a = (float)n * inv;
        float s, c;
        sincosf(a, &s, &c);
        rope[n * 64 + 2 * j] = s;
        rope[n * 64 + 2 * j + 1] = c;
    }
    if (idx < 32768) {
        int q = idx & 63, pp = (idx >> 6) & 63, h = idx >> 12;
        int r1 = pp >> 3, c1 = pp & 7, r2 = q >> 3, c2 = q & 7;
        int ri = (r1 - r2 + 7) * 15 + (c1 - c2 + 7);
        biasf[idx] = btab[ri * 8 + h];
    }
}

// ---------------------------------------------------------------------------
// LayerNorm over C=512 with NCHW->(B,N,C) transpose, bf16 out. 32 tokens/block.
// ---------------------------------------------------------------------------
__global__ __launch_bounds__(256) void ln_kernel(
    const float* __restrict__ x, const float* __restrict__ g,
    const float* __restrict__ be, u16* __restrict__ out)
{
    __shared__ u16 sX[512 * 33];
    __shared__ float sSum[256];
    __shared__ float sSq[256];
    __shared__ float sMu[32], sInv[32];

    const int tid = threadIdx.x;
    const int b = blockIdx.x >> 7, grp = blockIdx.x & 127;
    const int nbase = grp << 5;
    const int no = tid & 31, cg = tid >> 5;

    const float* xp = x + ((size_t)b << 21) + nbase + no;
    float sum = 0.f, sq = 0.f;
#pragma unroll 4
    for (int i = 0; i < 64; i++) {
        int c = (i << 3) + cg;
        float v = xp[(size_t)c << 12];
        sum += v;
        sq += v * v;
        sX[c * 33 + no] = f2bf(v);
    }
    sSum[tid] = sum;
    sSq[tid] = sq;
    __syncthreads();
    if (tid < 32) {
        float s = 0.f, q = 0.f;
#pragma unroll
        for (int k = 0; k < 8; k++) { s += sSum[k * 32 + tid]; q += sSq[k * 32 + tid]; }
        float mu = s * (1.f / 512.f);
        float var = q * (1.f / 512.f) - mu * mu;
        sMu[tid] = mu;
        sInv[tid] = rsqrtf(var + 1e-5f);
    }
    __syncthreads();

    const int t = tid >> 3;         // 0..31
    const int cs = (tid & 7) << 3;  // 0..56
    float mu = sMu[t], inv = sInv[t];
    size_t orow = ((size_t)((b << 12) + nbase + t)) * 512;
#pragma unroll
    for (int it = 0; it < 8; it++) {
        int c0 = cs + (it << 6);
        f32x4 g0 = *(const f32x4*)&g[c0];
        f32x4 g1 = *(const f32x4*)&g[c0 + 4];
        f32x4 e0 = *(const f32x4*)&be[c0];
        f32x4 e1 = *(const f32x4*)&be[c0 + 4];
        u16x8 o;
#pragma unroll
        for (int k = 0; k < 8; k++) {
            float v = bf2f(sX[(c0 + k) * 33 + t]);
            float gg = (k < 4) ? g0[k] : g1[k - 4];
            float bb = (k < 4) ? e0[k] : e1[k - 4];
            o[k] = f2bf((v - mu) * inv * gg + bb);
        }
        *(u16x8*)&out[orow + c0] = o;  // 8 consecutive threads -> 128B contiguous
    }
}

// ---------------------------------------------------------------------------
// Q/K projection GEMM: (32768,512)@(512,512)^T + bias, RoPE, window-permuted rows.
// 128x128 tile, BK=32, global_load_lds staging. grid (256,4).
// ---------------------------------------------------------------------------
template <bool ROPE>
__global__ __launch_bounds__(256) void gemm_proj(
    const u16* __restrict__ A, const u16* __restrict__ Bw,
    const float* __restrict__ bias, const float* __restrict__ rope,
    u16* __restrict__ Out)
{
    __shared__ u16 sA[128 * 32];
    __shared__ u16 sB[128 * 32];
    __shared__ u16 sC[64 * 136];

    const int m0 = blockIdx.x * 128;
    const int n0 = blockIdx.y * 128;
    const int tid = threadIdx.x;
    const int lane = tid & 63, wave = tid >> 6;
    const int ln = lane & 15, lq = lane >> 4;
    const int wm = wave & 1, wn = wave >> 1;

    const int srow = wave * 16 + (lane >> 2);
    const int sseg = (lane & 3) << 3;
    const u16* gA0 = A + (size_t)(m0 + srow) * 512 + sseg;
    const u16* gA1 = gA0 + (size_t)64 * 512;
    const u16* gB0 = Bw + (size_t)(n0 + srow) * 512 + sseg;
    const u16* gB1 = gB0 + (size_t)64 * 512;
    u16* lA0 = &sA[wave * 16 * 32];
    u16* lA1 = &sA[(64 + wave * 16) * 32];
    u16* lB0 = &sB[wave * 16 * 32];
    u16* lB1 = &sB[(64 + wave * 16) * 32];

    f32x4 acc[4][4] = {};

    for (int kt = 0; kt < 512; kt += 32) {
        gl_lds16(gA0 + kt, lA0);
        gl_lds16(gA1 + kt, lA1);
        gl_lds16(gB0 + kt, lB0);
        gl_lds16(gB1 + kt, lB1);
        __syncthreads();
        bf16x8 af[4], bfr[4];
#pragma unroll
        for (int i = 0; i < 4; i++)
            af[i] = *(const bf16x8*)&sA[(wm * 64 + i * 16 + ln) * 32 + lq * 8];
#pragma unroll
        for (int j = 0; j < 4; j++)
            bfr[j] = *(const bf16x8*)&sB[(wn * 64 + j * 16 + ln) * 32 + lq * 8];
#pragma unroll
        for (int i = 0; i < 4; i++)
#pragma unroll
            for (int j = 0; j < 4; j++)
                acc[i][j] = mfma16(af[i], bfr[j], acc[i][j]);
        __syncthreads();
    }

    float bj[4];
#pragma unroll
    for (int j = 0; j < 4; j++) bj[j] = bias[n0 + wn * 64 + j * 16 + ln];

#pragma unroll
    for (int half = 0; half < 2; half++) {
        __syncthreads();
        if (wm == half) {
#pragma unroll
            for (int i = 0; i < 4; i++)
#pragma unroll
                for (int j = 0; j < 4; j++)
#pragma unroll
                    for (int r = 0; r < 4; r++)
                        sC[(i * 16 + lq * 4 + r) * 136 + wn * 64 + j * 16 + ln] =
                            f2bf(acc[i][j][r] + bj[j]);
        }
        __syncthreads();
#pragma unroll
        for (int it = 0; it < 4; it++) {
            int idx = it * 256 + tid;
            int row = idx >> 4;
            int cseg = (idx & 15) * 8;
            u16x8 v = *(const u16x8*)&sC[row * 136 + cseg];
            int t = m0 + half * 64 + row;
            int n = t & 4095, bb = t >> 12;
            float f[8];
#pragma unroll
            for (int k = 0; k < 8; k++) f[k] = bf2f(v[k]);
            if (ROPE) {
                int d0 = cseg & 63;
                const float* rp = &rope[n * 64 + d0];
                f32x4 r0 = *(const f32x4*)rp;
                f32x4 r1 = *(const f32x4*)(rp + 4);
#pragma unroll
                for (int p = 0; p < 4; p++) {
                    float sn = (p < 2) ? r0[2 * p] : r1[2 * (p - 2)];
                    float cs = (p < 2) ? r0[2 * p + 1] : r1[2 * (p - 2) + 1];
                    float x0 = f[2 * p], x1 = f[2 * p + 1];
                    f[2 * p] = x0 * cs - x1 * sn;
                    f[2 * p + 1] = x0 * sn + x1 * cs;
                }
            }
            u16x8 o;
#pragma unroll
            for (int k = 0; k < 8; k++) o[k] = f2bf(f[k]);
            int wp = swapb(n);
            *(u16x8*)&Out[(size_t)((bb << 12) + wp) * 512 + n0 + cseg] = o;
        }
    }
}

// ---------------------------------------------------------------------------
// V projection GEMM: A rows staged in window-permuted order; output written
// TRANSPOSED to VT[(b,h,d)][wpos]. grid (256,4).
// ---------------------------------------------------------------------------
__global__ __launch_bounds__(256) void gemm_v(
    const u16* __restrict__ A, const u16* __restrict__ Bw,
    const float* __restrict__ bias, u16* __restrict__ VT)
{
    __shared__ u16 sA[128 * 32];
    __shared__ u16 sB[128 * 32];
    __shared__ u16 sCv[128 * 72];  // [col][token-local]

    const int m0 = blockIdx.x * 128;
    const int n0 = blockIdx.y * 128;
    const int tid = threadIdx.x;
    const int lane = tid & 63, wave = tid >> 6;
    const int ln = lane & 15, lq = lane >> 4;
    const int wm = wave & 1, wn = wave >> 1;

    const int wq0 = m0 & 4095;
    const int bhi = m0 & ~4095;
    const int bb = m0 >> 12;

    const int srow = wave * 16 + (lane >> 2);
    const int sseg = (lane & 3) << 3;
    const int nA0 = swapb(wq0 + srow);
    const int nA1 = swapb(wq0 + 64 + srow);
    const u16* gA0 = A + (size_t)(bhi + nA0) * 512 + sseg;
    const u16* gA1 = A + (size_t)(bhi + nA1) * 512 + sseg;
    const u16* gB0 = Bw + (size_t)(n0 + srow) * 512 + sseg;
    const u16* gB1 = gB0 + (size_t)64 * 512;
    u16* lA0 = &sA[wave * 16 * 32];
    u16* lA1 = &sA[(64 + wave * 16) * 32];
    u16* lB0 = &sB[wave * 16 * 32];
    u16* lB1 = &sB[(64 + wave * 16) * 32];

    f32x4 acc[4][4] = {};

    for (int kt = 0; kt < 512; kt += 32) {
        gl_lds16(gA0 + kt, lA0);
        gl_lds16(gA1 + kt, lA1);
        gl_lds16(gB0 + kt, lB0);
        gl_lds16(gB1 + kt, lB1);
        __syncthreads();
        bf16x8 af[4], bfr[4];
#pragma unroll
        for (int i = 0; i < 4; i++)
            af[i] = *(const bf16x8*)&sA[(wm * 64 + i * 16 + ln) * 32 + lq * 8];
#pragma unroll
        for (int j = 0; j < 4; j++)
            bfr[j] = *(const bf16x8*)&sB[(wn * 64 + j * 16 + ln) * 32 + lq * 8];
#pragma unroll
        for (int i = 0; i < 4; i++)
#pragma unroll
            for (int j = 0; j < 4; j++)
                acc[i][j] = mfma16(af[i], bfr[j], acc[i][j]);
        __syncthreads();
    }

    float bj[4];
#pragma unroll
    for (int j = 0; j < 4; j++) bj[j] = bias[n0 + wn * 64 + j * 16 + ln];

#pragma unroll
    for (int half = 0; half < 2; half++) {
        __syncthreads();
        if (wm == half) {
#pragma unroll
            for (int i = 0; i < 4; i++)
#pragma unroll
                for (int j = 0; j < 4; j++) {
                    u16x4 pk;
#pragma unroll
                    for (int r = 0; r < 4; r++) pk[r] = f2bf(acc[i][j][r] + bj[j]);
                    *(u16x4*)&sCv[(wn * 64 + j * 16 + ln) * 72 + i * 16 + lq * 4] = pk;
                }
        }
        __syncthreads();
#pragma unroll
        for (int ii = 0; ii < 4; ii++) {
            int idx = ii * 256 + tid;
            int col = idx >> 3, ch = (idx & 7) << 3;
            u16x8 v = *(const u16x8*)&sCv[col * 72 + ch];
            int c = n0 + col;
            int hh = c >> 6, dd = c & 63;
            *(u16x8*)&VT[((size_t)((((bb << 3) + hh) << 6) + dd)) * 4096 + wq0 + half * 64 + ch] = v;
        }
    }
}

// ---------------------------------------------------------------------------
// Output projection + bias + residual(qn) + un-permute + transpose to (B,C,N) f32.
// grid (256,4).
// ---------------------------------------------------------------------------
__global__ __launch_bounds__(256) void gemm_out(
    const u16* __restrict__ A, const u16* __restrict__ Bw,
    const float* __restrict__ bias, const u16* __restrict__ qn,
    float* __restrict__ Out)
{
    __shared__ u16 sA[128 * 32];
    __shared__ u16 sB[128 * 32];

    const int m0 = blockIdx.x * 128;
    const int n0 = blockIdx.y * 128;
    const int tid = threadIdx.x;
    const int lane = tid & 63, wave = tid >> 6;
    const int ln = lane & 15, lq = lane >> 4;
    const int wm = wave & 1, wn = wave >> 1;

    const int srow = wave * 16 + (lane >> 2);
    const int sseg = (lane & 3) << 3;
    const u16* gA0 = A + (size_t)(m0 + srow) * 512 + sseg;
    const u16* gA1 = gA0 + (size_t)64 * 512;
    const u16* gB0 = Bw + (size_t)(n0 + srow) * 512 + sseg;
    const u16* gB1 = gB0 + (size_t)64 * 512;
    u16* lA0 = &sA[wave * 16 * 32];
    u16* lA1 = &sA[(64 + wave * 16) * 32];
    u16* lB0 = &sB[wave * 16 * 32];
    u16* lB1 = &sB[(64 + wave * 16) * 32];

    f32x4 acc[4][4] = {};

    for (int kt = 0; kt < 512; kt += 32) {
        gl_lds16(gA0 + kt, lA0);
        gl_lds16(gA1 + kt, lA1);
        gl_lds16(gB0 + kt, lB0);
        gl_lds16(gB1 + kt, lB1);
        __syncthreads();
        bf16x8 af[4], bfr[4];
#pragma unroll
        for (int i = 0; i < 4; i++)
            af[i] = *(const bf16x8*)&sA[(wm * 64 + i * 16 + ln) * 32 + lq * 8];
#pragma unroll
        for (int j = 0; j < 4; j++)
            bfr[j] = *(const bf16x8*)&sB[(wn * 64 + j * 16 + ln) * 32 + lq * 8];
#pragma unroll
        for (int i = 0; i < 4; i++)
#pragma unroll
            for (int j = 0; j < 4; j++)
                acc[i][j] = mfma16(af[i], bfr[j], acc[i][j]);
        __syncthreads();
    }

    int cj[4];
    float bj[4];
#pragma unroll
    for (int j = 0; j < 4; j++) {
        cj[j] = n0 + wn * 64 + j * 16 + ln;
        bj[j] = bias[cj[j]];
    }
#pragma unroll
    for (int i = 0; i < 4; i++) {
        int t0 = m0 + wm * 64 + i * 16 + lq * 4;  // window-permuted row id
        int bb = t0 >> 12;
        int nb = swapb(t0 & 4095);                // original token; +r stays contiguous
#pragma unroll
        for (int j = 0; j < 4; j++) {
            f32x4 v;
#pragma unroll
            for (int r = 0; r < 4; r++)
                v[r] = acc[i][j][r] + bj[j] +
                       bf2f(qn[((size_t)(bb << 12) + nb + r) * 512 + cj[j]]);
            *(f32x4*)&Out[((size_t)((bb << 9) + cj[j]) << 12) + nb] = v;
        }
    }
}

// ---------------------------------------------------------------------------
// Windowed attention: block = (b, window, head); everything contiguous now.
// grid 4096: h = bid&7, w = (bid>>3)&63, b = bid>>9.
// ---------------------------------------------------------------------------
__global__ __launch_bounds__(256) void attn_kernel(
    const u16* __restrict__ Q, const u16* __restrict__ K, const u16* __restrict__ VT,
    const float* __restrict__ biasf, u16* __restrict__ Out)
{
    __shared__ u16 sQ[64 * 72];   // reused as output staging
    __shared__ u16 sK[64 * 72];
    __shared__ u16 sVT[64 * 72];  // [d][token]
    __shared__ u16 sP[4][16 * 72];

    const int tid = threadIdx.x;
    const int h = blockIdx.x & 7;
    const int w = (blockIdx.x >> 3) & 63;
    const int b = blockIdx.x >> 9;
    const int lane = tid & 63, wave = tid >> 6;
    const int ln = lane & 15, lq = lane >> 4;

    const size_t qrow0 = (size_t)(b << 12) + w * 64;
    const size_t vrow0 = ((size_t)(((b << 3) + h) << 6)) * 4096 + w * 64;

#pragma unroll
    for (int ii = 0; ii < 2; ii++) {
        int idx = ii * 256 + tid;
        int row = idx >> 3, ch = (idx & 7) << 3;
        size_t ga = (qrow0 + row) * 512 + h * 64 + ch;
        *(u16x8*)&sQ[row * 72 + ch] = *(const u16x8*)&Q[ga];
        *(u16x8*)&sK[row * 72 + ch] = *(const u16x8*)&K[ga];
        *(u16x8*)&sVT[row * 72 + ch] = *(const u16x8*)&VT[vrow0 + (size_t)row * 4096 + ch];
    }
    __syncthreads();

    f32x4 s[4] = {};
#pragma unroll
    for (int ks = 0; ks < 2; ks++) {
        bf16x8 a = *(const bf16x8*)&sQ[(wave * 16 + ln) * 72 + ks * 32 + lq * 8];
#pragma unroll
        for (int j = 0; j < 4; j++) {
            bf16x8 bb = *(const bf16x8*)&sK[(j * 16 + ln) * 72 + ks * 32 + lq * 8];
            s[j] = mfma16(a, bb, s[j]);
        }
    }

    float sv[4][4];
#pragma unroll
    for (int r = 0; r < 4; r++) {
        const float* bp = &biasf[((h * 64 + wave * 16 + lq * 4 + r) << 6) + ln];
#pragma unroll
        for (int j = 0; j < 4; j++) sv[r][j] = s[j][r] * 0.125f + bp[j * 16];
    }
#pragma unroll
    for (int r = 0; r < 4; r++) {
        float m = fmaxf(fmaxf(sv[r][0], sv[r][1]), fmaxf(sv[r][2], sv[r][3]));
        m = fmaxf(m, __shfl_xor(m, 1));
        m = fmaxf(m, __shfl_xor(m, 2));
        m = fmaxf(m, __shfl_xor(m, 4));
        m = fmaxf(m, __shfl_xor(m, 8));
        float sum = 0.f;
#pragma unroll
        for (int j = 0; j < 4; j++) {
            sv[r][j] = __expf(sv[r][j] - m);
            sum += sv[r][j];
        }
        sum += __shfl_xor(sum, 1);
        sum += __shfl_xor(sum, 2);
        sum += __shfl_xor(sum, 4);
        sum += __shfl_xor(sum, 8);
        float rinv = 1.f / sum;
#pragma unroll
        for (int j = 0; j < 4; j++)
            sP[wave][(lq * 4 + r) * 72 + j * 16 + ln] = f2bf(sv[r][j] * rinv);
    }
    // wave-private strip: no barrier needed

    f32x4 o[4] = {};
#pragma unroll
    for (int ks = 0; ks < 2; ks++) {
        bf16x8 a = *(const bf16x8*)&sP[wave][ln * 72 + ks * 32 + lq * 8];
#pragma unroll
        for (int jd = 0; jd < 4; jd++) {
            bf16x8 bb = *(const bf16x8*)&sVT[(jd * 16 + ln) * 72 + ks * 32 + lq * 8];
            o[jd] = mfma16(a, bb, o[jd]);
        }
    }

    // stage output (rows are wave-private in sQ), then coalesced 128B-row writes
#pragma unroll
    for (int r = 0; r < 4; r++)
#pragma unroll
        for (int jd = 0; jd < 4; jd++)
            sQ[(wave * 16 + lq * 4 + r) * 72 + jd * 16 + ln] = f2bf(o[jd][r]);
    __syncthreads();
#pragma unroll
    for (int ii = 0; ii < 2; ii++) {
        int idx = ii * 256 + tid;
        int row = idx >> 3, ch = (idx & 7) << 3;
        *(u16x8*)&Out[(qrow0 + row) * 512 + h * 64 + ch] = *(const u16x8*)&sQ[row * 72 + ch];
    }
}

// ---------------------------------------------------------------------------
extern "C" void kernel_launch(void* const* d_in, const int* in_sizes, int n_in,
                              void* d_out, int out_size, void* d_ws, size_t ws_size,
                              hipStream_t stream)
{
    const float* q    = (const float*)d_in[0];
    const float* kv   = (const float*)d_in[1];
    const float* g_q  = (const float*)d_in[2];
    const float* b_q  = (const float*)d_in[3];
    const float* g_kv = (const float*)d_in[4];
    const float* b_kv = (const float*)d_in[5];
    const float* Wq   = (const float*)d_in[6];
    const float* bq   = (const float*)d_in[7];
    const float* Wk   = (const float*)d_in[8];
    const float* bk   = (const float*)d_in[9];
    const float* Wv   = (const float*)d_in[10];
    const float* bv   = (const float*)d_in[11];
    const float* Wo   = (const float*)d_in[12];
    const float* bo   = (const float*)d_in[13];
    const float* btab = (const float*)d_in[14];

    char* ws = (char*)d_ws;
    u16* qn      = (u16*)(ws);                 // 33,554,432 B  (token order)
    u16* kvn     = (u16*)(ws + 33554432);      // 33,554,432 B  (reused as attn out)
    u16* VT      = (u16*)(ws + 67108864);      // 33,554,432 B  (b,h,d,wpos)
    float* rope  = (float*)(ws + 100663296);   // 1,048,576 B
    float* biasf = (float*)(ws + 101711872);   // 131,072 B
    u16* wq      = (u16*)(ws + 101842944);     // 4 x 524,288 B
    u16* wk      = (u16*)(ws + 102367232);
    u16* wv      = (u16*)(ws + 102891520);
    u16* wo      = (u16*)(ws + 103415808);
    u16* aout    = kvn;                        // safe: kvn consumed by K/V projections
    u16* Qr      = (u16*)d_out;                // d_out as scratch for Q/K (bf16)
    u16* Kr      = Qr + 16777216;

    setup_kernel<<<4096, 256, 0, stream>>>(Wq, Wk, Wv, Wo, btab, wq, wk, wv, wo, rope, biasf);
    ln_kernel<<<1024, 256, 0, stream>>>(q, g_q, b_q, qn);
    ln_kernel<<<1024, 256, 0, stream>>>(kv, g_kv, b_kv, kvn);
    gemm_proj<true><<<dim3(256, 4), 256, 0, stream>>>(qn, wq, bq, rope, Qr);
    gemm_proj<true><<<dim3(256, 4), 256, 0, stream>>>(kvn, wk, bk, rope, Kr);
    gemm_v<<<dim3(256, 4), 256, 0, stream>>>(kvn, wv, bv, VT);
    attn_kernel<<<4096, 256, 0, stream>>>(Qr, Kr, VT, biasf, aout);
    gemm_out<<<dim3(256, 4), 256, 0, stream>>>(aout, wo, bo, qn, (float*)d_out);
}

// Round 3
// 362.763 us; speedup vs baseline: 1.0571x; 1.0078x over previous
//
#include <hip/hip_runtime.h>

// Problem: B=8, C=512, H=W=64, NH=8, D=64, window 8x8 (Ws=64), N=4096.
// Token dim is window-permuted AT THE LAYERNORM (bit-swap n[8:6]<->n[5:3], involution):
// qn/kvn/Q/K/V/attn-out all live in permuted space (windows contiguous); un-permute
// happens only in gemm_out's final transposed store. V stored transposed (b,h,d,wpos).

typedef unsigned short u16;
typedef __bf16 bf16x8 __attribute__((ext_vector_type(8)));
typedef float f32x4 __attribute__((ext_vector_type(4)));
typedef u16 u16x8 __attribute__((ext_vector_type(8)));
typedef u16 u16x4 __attribute__((ext_vector_type(4)));

__device__ __forceinline__ u16 f2bf(float f) {
    __bf16 h = (__bf16)f;
    return __builtin_bit_cast(u16, h);
}
__device__ __forceinline__ float bf2f(u16 u) {
    return (float)__builtin_bit_cast(__bf16, u);
}
__device__ __forceinline__ f32x4 mfma16(bf16x8 a, bf16x8 b, f32x4 c) {
    return __builtin_amdgcn_mfma_f32_16x16x32_bf16(a, b, c, 0, 0, 0);
}
__device__ __forceinline__ void gl_lds16(const u16* g, u16* l) {
    __builtin_amdgcn_global_load_lds((const __attribute__((address_space(1))) void*)g,
                                     (__attribute__((address_space(3))) void*)l, 16, 0, 0);
}
// window permutation: n = hn[11:9] r[8:6] wn[5:3] cc[2:0] -> hn wn r cc  (involution)
__device__ __forceinline__ int swapb(int n) {
    return (n & 0xE07) | ((n & 0x1C0) >> 3) | ((n & 0x038) << 3);
}

// ---------------------------------------------------------------------------
// Setup: bf16 weights, RoPE table (4096 x 64 [sin,cos] interleaved), bias (8,64,64).
// ---------------------------------------------------------------------------
__global__ __launch_bounds__(256) void setup_kernel(
    const float* __restrict__ Wq, const float* __restrict__ Wk,
    const float* __restrict__ Wv, const float* __restrict__ Wo,
    const float* __restrict__ btab,
    u16* __restrict__ wq, u16* __restrict__ wk,
    u16* __restrict__ wv, u16* __restrict__ wo,
    float* __restrict__ rope, float* __restrict__ biasf)
{
    int idx = blockIdx.x * 256 + threadIdx.x;
    {
        int w = idx >> 18, e = idx & 262143;
        const float* src = (w == 0) ? Wq : (w == 1) ? Wk : (w == 2) ? Wv : Wo;
        u16* dst = (w == 0) ? wq : (w == 1) ? wk : (w == 2) ? wv : wo;
        dst[e] = f2bf(src[e]);
    }
    if (idx < 131072) {
        int n = idx >> 5, j = idx & 31;
        float inv = powf(10000.0f, -(float)j / 32.0f);
        float a = (float)n * inv;
        float s, c;
        sincosf(a, &s, &c);
        rope[n * 64 + 2 * j] = s;
        rope[n * 64 + 2 * j + 1] = c;
    }
    if (idx < 32768) {
        int q = idx & 63, pp = (idx >> 6) & 63, h = idx >> 12;
        int r1 = pp >> 3, c1 = pp & 7, r2 = q >> 3, c2 = q & 7;
        int ri = (r1 - r2 + 7) * 15 + (c1 - c2 + 7);
        biasf[idx] = btab[ri * 8 + h];
    }
}

// ---------------------------------------------------------------------------
// LayerNorm over C=512, NCHW -> (B,Nperm,C) bf16, float4-vectorized input.
// Block: 32 consecutive tokens. grid = 1024.
// ---------------------------------------------------------------------------
__global__ __launch_bounds__(256) void ln_kernel(
    const float* __restrict__ x, const float* __restrict__ g,
    const float* __restrict__ be, u16* __restrict__ out)
{
    __shared__ u16 sX[512 * 36];  // [c][token], stride 36 (8B-aligned u16x4 stores)
    __shared__ float sS[1024];
    __shared__ float sQ[1024];
    __shared__ float sMu[32], sInv[32];

    const int tid = threadIdx.x;
    const int b = blockIdx.x >> 7, grp = blockIdx.x & 127;
    const int nbase = grp << 5;
    const int t4 = tid & 7;   // token quad (4 tokens each)
    const int cg = tid >> 3;  // 32 channels per iteration

    const float* xp = x + ((size_t)b << 21) + nbase + (t4 << 2);
    float sm[4] = {0.f, 0.f, 0.f, 0.f}, sq2[4] = {0.f, 0.f, 0.f, 0.f};
#pragma unroll 4
    for (int it = 0; it < 16; it++) {
        int c = (it << 5) + cg;
        f32x4 v = *(const f32x4*)&xp[(size_t)c << 12];
        u16x4 h;
#pragma unroll
        for (int r = 0; r < 4; r++) {
            sm[r] += v[r];
            sq2[r] += v[r] * v[r];
            h[r] = f2bf(v[r]);
        }
        *(u16x4*)&sX[c * 36 + (t4 << 2)] = h;
    }
#pragma unroll
    for (int r = 0; r < 4; r++) {
        sS[tid * 4 + r] = sm[r];
        sQ[tid * 4 + r] = sq2[r];
    }
    __syncthreads();
    if (tid < 32) {  // token tid: t4v = tid>>2, r = tid&3
        int t4v = tid >> 2, r = tid & 3;
        float a = 0.f, q2 = 0.f;
#pragma unroll
        for (int c2 = 0; c2 < 32; c2++) {
            int i2 = ((c2 << 3) + t4v) * 4 + r;
            a += sS[i2];
            q2 += sQ[i2];
        }
        float mu = a * (1.f / 512.f);
        float var = q2 * (1.f / 512.f) - mu * mu;
        sMu[tid] = mu;
        sInv[tid] = rsqrtf(var + 1e-5f);
    }
    __syncthreads();

    const int t = tid >> 3;         // 0..31
    const int cs = (tid & 7) << 3;  // 0..56
    float mu = sMu[t], inv = sInv[t];
    int p = swapb(nbase + t);  // permuted row
    size_t orow = ((size_t)((b << 12) + p)) * 512;
#pragma unroll
    for (int it = 0; it < 8; it++) {
        int c0 = cs + (it << 6);
        f32x4 g0 = *(const f32x4*)&g[c0];
        f32x4 g1 = *(const f32x4*)&g[c0 + 4];
        f32x4 e0 = *(const f32x4*)&be[c0];
        f32x4 e1 = *(const f32x4*)&be[c0 + 4];
        u16x8 o;
#pragma unroll
        for (int k = 0; k < 8; k++) {
            float v = bf2f(sX[(c0 + k) * 36 + t]);
            float gg = (k < 4) ? g0[k] : g1[k - 4];
            float bb = (k < 4) ? e0[k] : e1[k - 4];
            o[k] = f2bf((v - mu) * inv * gg + bb);
        }
        *(u16x8*)&out[orow + c0] = o;
    }
}

// ---------------------------------------------------------------------------
// Fused Q/K/V projection. grid (256, 12): kind = y>>2 (0=Q,1=K,2=V), n0=(y&3)*128.
// A rows are permuted tokens; Q/K epilogue applies RoPE (n = swapb(row)) and writes
// contiguous rows; V epilogue writes transposed (b,h,d,wpos).
// ---------------------------------------------------------------------------
__global__ __launch_bounds__(256) void gemm_qkv(
    const u16* __restrict__ qn, const u16* __restrict__ kvn,
    const u16* __restrict__ wq, const u16* __restrict__ wk, const u16* __restrict__ wv,
    const float* __restrict__ bq, const float* __restrict__ bk, const float* __restrict__ bv,
    const float* __restrict__ rope,
    u16* __restrict__ Qr, u16* __restrict__ Kr, u16* __restrict__ VT)
{
    __shared__ u16 sA[128 * 32];
    __shared__ u16 sB[128 * 32];
    __shared__ u16 sU[9216];  // Q/K: 64x136 C-transpose; V: 128x72 col-major stage

    const int kind = blockIdx.y >> 2;
    const int n0 = (blockIdx.y & 3) * 128;
    const u16* A = (kind == 0) ? qn : kvn;
    const u16* W = (kind == 0) ? wq : (kind == 1) ? wk : wv;
    const float* bias = (kind == 0) ? bq : (kind == 1) ? bk : bv;

    const int m0 = blockIdx.x * 128;
    const int tid = threadIdx.x;
    const int lane = tid & 63, wave = tid >> 6;
    const int ln = lane & 15, lq = lane >> 4;
    const int wm = wave & 1, wn = wave >> 1;

    const int srow = wave * 16 + (lane >> 2);
    const int sseg = (lane & 3) << 3;
    const u16* gA0 = A + (size_t)(m0 + srow) * 512 + sseg;
    const u16* gA1 = gA0 + (size_t)64 * 512;
    const u16* gB0 = W + (size_t)(n0 + srow) * 512 + sseg;
    const u16* gB1 = gB0 + (size_t)64 * 512;
    u16* lA0 = &sA[wave * 16 * 32];
    u16* lA1 = &sA[(64 + wave * 16) * 32];
    u16* lB0 = &sB[wave * 16 * 32];
    u16* lB1 = &sB[(64 + wave * 16) * 32];

    f32x4 acc[4][4] = {};

    for (int kt = 0; kt < 512; kt += 32) {
        gl_lds16(gA0 + kt, lA0);
        gl_lds16(gA1 + kt, lA1);
        gl_lds16(gB0 + kt, lB0);
        gl_lds16(gB1 + kt, lB1);
        __syncthreads();
        bf16x8 af[4], bfr[4];
#pragma unroll
        for (int i = 0; i < 4; i++)
            af[i] = *(const bf16x8*)&sA[(wm * 64 + i * 16 + ln) * 32 + lq * 8];
#pragma unroll
        for (int j = 0; j < 4; j++)
            bfr[j] = *(const bf16x8*)&sB[(wn * 64 + j * 16 + ln) * 32 + lq * 8];
#pragma unroll
        for (int i = 0; i < 4; i++)
#pragma unroll
            for (int j = 0; j < 4; j++)
                acc[i][j] = mfma16(af[i], bfr[j], acc[i][j]);
        __syncthreads();
    }

    float bj[4];
#pragma unroll
    for (int j = 0; j < 4; j++) bj[j] = bias[n0 + wn * 64 + j * 16 + ln];

    if (kind < 2) {
        u16* Out = (kind == 0) ? Qr : Kr;
#pragma unroll
        for (int half = 0; half < 2; half++) {
            __syncthreads();
            if (wm == half) {
#pragma unroll
                for (int i = 0; i < 4; i++)
#pragma unroll
                    for (int j = 0; j < 4; j++)
#pragma unroll
                        for (int r = 0; r < 4; r++)
                            sU[(i * 16 + lq * 4 + r) * 136 + wn * 64 + j * 16 + ln] =
                                f2bf(acc[i][j][r] + bj[j]);
            }
            __syncthreads();
#pragma unroll
            for (int it = 0; it < 4; it++) {
                int idx = it * 256 + tid;
                int row = idx >> 4;
                int cseg = (idx & 15) * 8;
                u16x8 v = *(const u16x8*)&sU[row * 136 + cseg];
                int t = m0 + half * 64 + row;   // permuted row id
                int n = swapb(t & 4095);        // original token for RoPE
                float f[8];
#pragma unroll
                for (int k = 0; k < 8; k++) f[k] = bf2f(v[k]);
                {
                    int d0 = cseg & 63;
                    const float* rp = &rope[n * 64 + d0];
                    f32x4 r0 = *(const f32x4*)rp;
                    f32x4 r1 = *(const f32x4*)(rp + 4);
#pragma unroll
                    for (int pp = 0; pp < 4; pp++) {
                        float sn = (pp < 2) ? r0[2 * pp] : r1[2 * (pp - 2)];
                        float cs2 = (pp < 2) ? r0[2 * pp + 1] : r1[2 * (pp - 2) + 1];
                        float x0 = f[2 * pp], x1 = f[2 * pp + 1];
                        f[2 * pp] = x0 * cs2 - x1 * sn;
                        f[2 * pp + 1] = x0 * sn + x1 * cs2;
                    }
                }
                u16x8 o;
#pragma unroll
                for (int k = 0; k < 8; k++) o[k] = f2bf(f[k]);
                *(u16x8*)&Out[(size_t)t * 512 + n0 + cseg] = o;
            }
        }
    } else {
        const int wq0 = m0 & 4095;
        const int bb = m0 >> 12;
#pragma unroll
        for (int half = 0; half < 2; half++) {
            __syncthreads();
            if (wm == half) {
#pragma unroll
                for (int i = 0; i < 4; i++)
#pragma unroll
                    for (int j = 0; j < 4; j++) {
                        u16x4 pk;
#pragma unroll
                        for (int r = 0; r < 4; r++) pk[r] = f2bf(acc[i][j][r] + bj[j]);
                        *(u16x4*)&sU[(wn * 64 + j * 16 + ln) * 72 + i * 16 + lq * 4] = pk;
                    }
            }
            __syncthreads();
#pragma unroll
            for (int ii = 0; ii < 4; ii++) {
                int idx = ii * 256 + tid;
                int col = idx >> 3, ch = (idx & 7) << 3;
                u16x8 v = *(const u16x8*)&sU[col * 72 + ch];
                int c = n0 + col;
                int hh = c >> 6, dd = c & 63;
                *(u16x8*)&VT[((size_t)((((bb << 3) + hh) << 6) + dd)) * 4096 +
                             wq0 + half * 64 + ch] = v;
            }
        }
    }
}

// ---------------------------------------------------------------------------
// Output projection + bias + residual(qn, LDS-staged) + un-permute + (B,C,N) f32.
// grid (256,4).
// ---------------------------------------------------------------------------
__global__ __launch_bounds__(256) void gemm_out(
    const u16* __restrict__ A, const u16* __restrict__ Bw,
    const float* __restrict__ bias, const u16* __restrict__ qn,
    float* __restrict__ Out)
{
    __shared__ u16 sA[128 * 32];
    __shared__ u16 sB[128 * 32];
    __shared__ u16 sR[128 * 136];  // residual tile [token][c]

    const int m0 = blockIdx.x * 128;
    const int n0 = blockIdx.y * 128;
    const int tid = threadIdx.x;
    const int lane = tid & 63, wave = tid >> 6;
    const int ln = lane & 15, lq = lane >> 4;
    const int wm = wave & 1, wn = wave >> 1;

    const int srow = wave * 16 + (lane >> 2);
    const int sseg = (lane & 3) << 3;
    const u16* gA0 = A + (size_t)(m0 + srow) * 512 + sseg;
    const u16* gA1 = gA0 + (size_t)64 * 512;
    const u16* gB0 = Bw + (size_t)(n0 + srow) * 512 + sseg;
    const u16* gB1 = gB0 + (size_t)64 * 512;
    u16* lA0 = &sA[wave * 16 * 32];
    u16* lA1 = &sA[(64 + wave * 16) * 32];
    u16* lB0 = &sB[wave * 16 * 32];
    u16* lB1 = &sB[(64 + wave * 16) * 32];

    f32x4 acc[4][4] = {};

    for (int kt = 0; kt < 512; kt += 32) {
        gl_lds16(gA0 + kt, lA0);
        gl_lds16(gA1 + kt, lA1);
        gl_lds16(gB0 + kt, lB0);
        gl_lds16(gB1 + kt, lB1);
        __syncthreads();
        bf16x8 af[4], bfr[4];
#pragma unroll
        for (int i = 0; i < 4; i++)
            af[i] = *(const bf16x8*)&sA[(wm * 64 + i * 16 + ln) * 32 + lq * 8];
#pragma unroll
        for (int j = 0; j < 4; j++)
            bfr[j] = *(const bf16x8*)&sB[(wn * 64 + j * 16 + ln) * 32 + lq * 8];
#pragma unroll
        for (int i = 0; i < 4; i++)
#pragma unroll
            for (int j = 0; j < 4; j++)
                acc[i][j] = mfma16(af[i], bfr[j], acc[i][j]);
        __syncthreads();
    }

    // stage residual tile: coalesced u16x8 rows (qn is permuted like A)
#pragma unroll
    for (int it = 0; it < 8; it++) {
        int idx = it * 256 + tid;
        int row = idx >> 4, c8 = (idx & 15) << 3;
        *(u16x8*)&sR[row * 136 + c8] = *(const u16x8*)&qn[(size_t)(m0 + row) * 512 + n0 + c8];
    }
    __syncthreads();

    int cj[4];
    float bj[4];
#pragma unroll
    for (int j = 0; j < 4; j++) {
        cj[j] = n0 + wn * 64 + j * 16 + ln;
        bj[j] = bias[cj[j]];
    }
#pragma unroll
    for (int i = 0; i < 4; i++) {
        int t0 = m0 + wm * 64 + i * 16 + lq * 4;  // permuted row id
        int bb = t0 >> 12;
        int nb = swapb(t0 & 4095);                // original token; +r contiguous
        int lrow = wm * 64 + i * 16 + lq * 4;
#pragma unroll
        for (int j = 0; j < 4; j++) {
            int lcol = wn * 64 + j * 16 + ln;
            f32x4 v;
#pragma unroll
            for (int r = 0; r < 4; r++)
                v[r] = acc[i][j][r] + bj[j] + bf2f(sR[(lrow + r) * 136 + lcol]);
            *(f32x4*)&Out[((size_t)((bb << 9) + cj[j]) << 12) + nb] = v;
        }
    }
}

// ---------------------------------------------------------------------------
// Windowed attention: block = (b, window, head); all inputs window-contiguous.
// grid 4096: h = bid&7, w = (bid>>3)&63, b = bid>>9.
// ---------------------------------------------------------------------------
__global__ __launch_bounds__(256) void attn_kernel(
    const u16* __restrict__ Q, const u16* __restrict__ K, const u16* __restrict__ VT,
    const float* __restrict__ biasf, u16* __restrict__ Out)
{
    __shared__ u16 sQ[64 * 72];   // reused as output staging
    __shared__ u16 sK[64 * 72];
    __shared__ u16 sVT[64 * 72];  // [d][token]
    __shared__ u16 sP[4][16 * 72];

    const int tid = threadIdx.x;
    const int h = blockIdx.x & 7;
    const int w = (blockIdx.x >> 3) & 63;
    const int b = blockIdx.x >> 9;
    const int lane = tid & 63, wave = tid >> 6;
    const int ln = lane & 15, lq = lane >> 4;

    const size_t qrow0 = (size_t)(b << 12) + w * 64;
    const size_t vrow0 = ((size_t)(((b << 3) + h) << 6)) * 4096 + w * 64;

#pragma unroll
    for (int ii = 0; ii < 2; ii++) {
        int idx = ii * 256 + tid;
        int row = idx >> 3, ch = (idx & 7) << 3;
        size_t ga = (qrow0 + row) * 512 + h * 64 + ch;
        *(u16x8*)&sQ[row * 72 + ch] = *(const u16x8*)&Q[ga];
        *(u16x8*)&sK[row * 72 + ch] = *(const u16x8*)&K[ga];
        *(u16x8*)&sVT[row * 72 + ch] = *(const u16x8*)&VT[vrow0 + (size_t)row * 4096 + ch];
    }
    __syncthreads();

    f32x4 s[4] = {};
#pragma unroll
    for (int ks = 0; ks < 2; ks++) {
        bf16x8 a = *(const bf16x8*)&sQ[(wave * 16 + ln) * 72 + ks * 32 + lq * 8];
#pragma unroll
        for (int j = 0; j < 4; j++) {
            bf16x8 bb = *(const bf16x8*)&sK[(j * 16 + ln) * 72 + ks * 32 + lq * 8];
            s[j] = mfma16(a, bb, s[j]);
        }
    }

    float sv[4][4];
#pragma unroll
    for (int r = 0; r < 4; r++) {
        const float* bp = &biasf[((h * 64 + wave * 16 + lq * 4 + r) << 6) + ln];
#pragma unroll
        for (int j = 0; j < 4; j++) sv[r][j] = s[j][r] * 0.125f + bp[j * 16];
    }
#pragma unroll
    for (int r = 0; r < 4; r++) {
        float m = fmaxf(fmaxf(sv[r][0], sv[r][1]), fmaxf(sv[r][2], sv[r][3]));
        m = fmaxf(m, __shfl_xor(m, 1));
        m = fmaxf(m, __shfl_xor(m, 2));
        m = fmaxf(m, __shfl_xor(m, 4));
        m = fmaxf(m, __shfl_xor(m, 8));
        float sum = 0.f;
#pragma unroll
        for (int j = 0; j < 4; j++) {
            sv[r][j] = __expf(sv[r][j] - m);
            sum += sv[r][j];
        }
        sum += __shfl_xor(sum, 1);
        sum += __shfl_xor(sum, 2);
        sum += __shfl_xor(sum, 4);
        sum += __shfl_xor(sum, 8);
        float rinv = 1.f / sum;
#pragma unroll
        for (int j = 0; j < 4; j++)
            sP[wave][(lq * 4 + r) * 72 + j * 16 + ln] = f2bf(sv[r][j] * rinv);
    }
    // wave-private strip: no barrier needed

    f32x4 o[4] = {};
#pragma unroll
    for (int ks = 0; ks < 2; ks++) {
        bf16x8 a = *(const bf16x8*)&sP[wave][ln * 72 + ks * 32 + lq * 8];
#pragma unroll
        for (int jd = 0; jd < 4; jd++) {
            bf16x8 bb = *(const bf16x8*)&sVT[(jd * 16 + ln) * 72 + ks * 32 + lq * 8];
            o[jd] = mfma16(a, bb, o[jd]);
        }
    }

#pragma unroll
    for (int r = 0; r < 4; r++)
#pragma unroll
        for (int jd = 0; jd < 4; jd++)
            sQ[(wave * 16 + lq * 4 + r) * 72 + jd * 16 + ln] = f2bf(o[jd][r]);
    __syncthreads();
#pragma unroll
    for (int ii = 0; ii < 2; ii++) {
        int idx = ii * 256 + tid;
        int row = idx >> 3, ch = (idx & 7) << 3;
        *(u16x8*)&Out[(qrow0 + row) * 512 + h * 64 + ch] = *(const u16x8*)&sQ[row * 72 + ch];
    }
}

// ---------------------------------------------------------------------------
extern "C" void kernel_launch(void* const* d_in, const int* in_sizes, int n_in,
                              void* d_out, int out_size, void* d_ws, size_t ws_size,
                              hipStream_t stream)
{
    const float* q    = (const float*)d_in[0];
    const float* kv   = (const float*)d_in[1];
    const float* g_q  = (const float*)d_in[2];
    const float* b_q  = (const float*)d_in[3];
    const float* g_kv = (const float*)d_in[4];
    const float* b_kv = (const float*)d_in[5];
    const float* Wq   = (const float*)d_in[6];
    const float* bq   = (const float*)d_in[7];
    const float* Wk   = (const float*)d_in[8];
    const float* bk   = (const float*)d_in[9];
    const float* Wv   = (const float*)d_in[10];
    const float* bv   = (const float*)d_in[11];
    const float* Wo   = (const float*)d_in[12];
    const float* bo   = (const float*)d_in[13];
    const float* btab = (const float*)d_in[14];

    char* ws = (char*)d_ws;
    u16* qn      = (u16*)(ws);                 // 33,554,432 B  (permuted token order)
    u16* kvn     = (u16*)(ws + 33554432);      // 33,554,432 B  (reused as attn out)
    u16* VT      = (u16*)(ws + 67108864);      // 33,554,432 B  (b,h,d,wpos)
    float* rope  = (float*)(ws + 100663296);   // 1,048,576 B
    float* biasf = (float*)(ws + 101711872);   // 131,072 B
    u16* wq      = (u16*)(ws + 101842944);     // 4 x 524,288 B
    u16* wk      = (u16*)(ws + 102367232);
    u16* wv      = (u16*)(ws + 102891520);
    u16* wo      = (u16*)(ws + 103415808);
    u16* aout    = kvn;                        // safe: kvn consumed by QKV projection
    u16* Qr      = (u16*)d_out;                // d_out as scratch for Q/K (bf16)
    u16* Kr      = Qr + 16777216;

    setup_kernel<<<4096, 256, 0, stream>>>(Wq, Wk, Wv, Wo, btab, wq, wk, wv, wo, rope, biasf);
    ln_kernel<<<1024, 256, 0, stream>>>(q, g_q, b_q, qn);
    ln_kernel<<<1024, 256, 0, stream>>>(kv, g_kv, b_kv, kvn);
    gemm_qkv<<<dim3(256, 12), 256, 0, stream>>>(qn, kvn, wq, wk, wv, bq, bk, bv, rope, Qr, Kr, VT);
    attn_kernel<<<4096, 256, 0, stream>>>(Qr, Kr, VT, biasf, aout);
    gemm_out<<<dim3(256, 4), 256, 0, stream>>>(aout, wo, bo, qn, (float*)d_out);
}